// Round 14
// baseline (30.203 us; speedup 1.0000x reference)
//
#include <hip/hip_runtime.h>
#include <math.h>

#define B 4
#define S 4096
#define N 4096
#define BLK 512            // 8 waves; 2 blocks/CU (LDS 64KB each)
#define NW 8
#define NBLK 512           // (S/32) * B
#define PASS 2048          // cloud pts per LDS pass per cloud
#define NPASS 2
#define JTW 8              // j-tiles (32 rows) per wave per pass = PASS/32/NW
#define INF 3.4e38f
#define SCALE 1099511627776.0   // 2^40 fixed-point scale

typedef _Float16 f16x8  __attribute__((ext_vector_type(8)));
typedef float    f32x16 __attribute__((ext_vector_type(16)));

// 32x32x16 K-packed Gram MFMA (mapping verified R12/R13), W=1 (32 s/block),
// full-N per block; single kernel: per-block sums merged via deterministic
// u64 fixed-point atomics; counter-elected last block writes out[B].
// A (cloud pt j): {-y0,-y1,-y2, hy_hi, hy_lo, 0,0,0}
// B (grid s, cols=lane&31): lanes<32 {x0,x1,x2,1,1,0,0,0}; lanes>=32 zero.
// D[j][s] = hy - x.y ; u = hx + min_j D ; d = sqrt(max(2u,0)).
__global__ __launch_bounds__(BLK, 4) void sdf_mfma(
    const float* __restrict__ grid,   // [B,S,3]
    const float* __restrict__ gts,    // [B,N,3]
    const float* __restrict__ preds,  // [B,N,3]
    unsigned long long* __restrict__ sum,  // [B] fixed-point accumulators
    unsigned* __restrict__ cnt,            // [1] block counter
    float* __restrict__ out)               // [B]
{
    __shared__ float4 Ap[PASS];       // 32 KB
    __shared__ float4 Ag[PASS];       // 32 KB

    const int tid   = threadIdx.x;
    const int lane  = tid & 63;
    const int wv    = tid >> 6;       // 0..7
    const int l31   = lane & 31;
    const int stile = blockIdx.x;     // 128 tiles of 32 s
    const int b     = blockIdx.y;
    const int scol  = stile * 32;

    // ---- B-frag + hx (cols = lane&31; lanes 32-63 zero kill k=8..15) ----
    const bool lo32 = (lane < 32);
    f16x8 bf;
    float hx;
    {
        const float* xp = grid + ((size_t)b * S + scol + l31) * 3;
        float x0 = (float)(_Float16)xp[0];
        float x1 = (float)(_Float16)xp[1];
        float x2 = (float)(_Float16)xp[2];
        hx = 0.5f * (x0 * x0 + x1 * x1 + x2 * x2);
        f16x8 bb = { (_Float16)x0, (_Float16)x1, (_Float16)x2,
                     (_Float16)1.f, (_Float16)1.f,
                     (_Float16)0.f, (_Float16)0.f, (_Float16)0.f };
        f16x8 z  = { (_Float16)0.f, (_Float16)0.f, (_Float16)0.f, (_Float16)0.f,
                     (_Float16)0.f, (_Float16)0.f, (_Float16)0.f, (_Float16)0.f };
        bf = lo32 ? bb : z;
    }

    const f32x16 zc = { 0.f, 0.f, 0.f, 0.f, 0.f, 0.f, 0.f, 0.f,
                        0.f, 0.f, 0.f, 0.f, 0.f, 0.f, 0.f, 0.f };
    float accp = INF, accg = INF;

    const float4* srcP = (const float4*)(preds + (size_t)b * N * 3);
    const float4* srcG = (const float4*)(gts   + (size_t)b * N * 3);

    for (int p = 0; p < NPASS; ++p) {
        if (p) __syncthreads();            // prior pass fully consumed
        // ---- stage + pack: thread tid handles pts [4*tid, 4*tid+4) ----
        {
            const int fo = p * (PASS * 3 / 4) + 3 * tid;   // float4 offset
            float4 r0 = srcP[fo], r1 = srcP[fo + 1], r2 = srcP[fo + 2];
            const float ys[4][3] = { { r0.x, r0.y, r0.z }, { r0.w, r1.x, r1.y },
                                     { r1.z, r1.w, r2.x }, { r2.y, r2.z, r2.w } };
            #pragma unroll
            for (int k = 0; k < 4; ++k) {
                float y0 = (float)(_Float16)ys[k][0];
                float y1 = (float)(_Float16)ys[k][1];
                float y2 = (float)(_Float16)ys[k][2];
                float hy = 0.5f * (y0 * y0 + y1 * y1 + y2 * y2);
                _Float16 hh = (_Float16)hy;
                _Float16 hl = (_Float16)(hy - (float)hh);
                f16x8 a = { (_Float16)(-y0), (_Float16)(-y1), (_Float16)(-y2),
                            hh, hl, (_Float16)0.f, (_Float16)0.f, (_Float16)0.f };
                *(f16x8*)&Ap[4 * tid + k] = a;
            }
            r0 = srcG[fo]; r1 = srcG[fo + 1]; r2 = srcG[fo + 2];
            const float yg[4][3] = { { r0.x, r0.y, r0.z }, { r0.w, r1.x, r1.y },
                                     { r1.z, r1.w, r2.x }, { r2.y, r2.z, r2.w } };
            #pragma unroll
            for (int k = 0; k < 4; ++k) {
                float y0 = (float)(_Float16)yg[k][0];
                float y1 = (float)(_Float16)yg[k][1];
                float y2 = (float)(_Float16)yg[k][2];
                float hy = 0.5f * (y0 * y0 + y1 * y1 + y2 * y2);
                _Float16 hh = (_Float16)hy;
                _Float16 hl = (_Float16)(hy - (float)hh);
                f16x8 g = { (_Float16)(-y0), (_Float16)(-y1), (_Float16)(-y2),
                            hh, hl, (_Float16)0.f, (_Float16)0.f, (_Float16)0.f };
                *(f16x8*)&Ag[4 * tid + k] = g;
            }
        }
        __syncthreads();

        // ---- compute: wave's JTW j-tiles of 32 rows ----
        const char* app = (const char*)Ap + ((size_t)wv * JTW * 32 + l31) * 16;
        const char* agp = (const char*)Ag + ((size_t)wv * JTW * 32 + l31) * 16;
        #pragma unroll
        for (int jt = 0; jt < JTW; ++jt) {
            const f16x8 afp = *(const f16x8*)(app + jt * 512);
            const f16x8 afg = *(const f16x8*)(agp + jt * 512);
            {
                f32x16 d = __builtin_amdgcn_mfma_f32_32x32x16_f16(afp, bf, zc, 0, 0, 0);
                // balanced tree fold (depth 5)
                float t0 = fminf(d[0],  d[1]),  t1 = fminf(d[2],  d[3]);
                float t2 = fminf(d[4],  d[5]),  t3 = fminf(d[6],  d[7]);
                float t4 = fminf(d[8],  d[9]),  t5 = fminf(d[10], d[11]);
                float t6 = fminf(d[12], d[13]), t7 = fminf(d[14], d[15]);
                float u0 = fminf(t0, t1), u1 = fminf(t2, t3);
                float u2 = fminf(t4, t5), u3 = fminf(t6, t7);
                accp = fminf(accp, fminf(fminf(u0, u1), fminf(u2, u3)));
            }
            {
                f32x16 d = __builtin_amdgcn_mfma_f32_32x32x16_f16(afg, bf, zc, 0, 0, 0);
                float t0 = fminf(d[0],  d[1]),  t1 = fminf(d[2],  d[3]);
                float t2 = fminf(d[4],  d[5]),  t3 = fminf(d[6],  d[7]);
                float t4 = fminf(d[8],  d[9]),  t5 = fminf(d[10], d[11]);
                float t6 = fminf(d[12], d[13]), t7 = fminf(d[14], d[15]);
                float u0 = fminf(t0, t1), u1 = fminf(t2, t3);
                float u2 = fminf(t4, t5), u3 = fminf(t6, t7);
                accg = fminf(accg, fminf(fminf(u0, u1), fminf(u2, u3)));
            }
        }
    }
    __syncthreads();   // all reads done; Ap reusable as sm

    // ---- cross-lane (row halves) + cross-wave + block tail ----
    float* sm = (float*)Ap;   // [NW][2][32]
    {
        float mp = fminf(accp, __shfl_xor(accp, 32, 64));
        float mg = fminf(accg, __shfl_xor(accg, 32, 64));
        if (lo32) {
            sm[(wv * 2 + 0) * 32 + l31] = hx + mp;
            sm[(wv * 2 + 1) * 32 + l31] = hx + mg;
        }
    }
    __syncthreads();
    if (tid < 32) {
        float mp = INF, mg = INF;
        #pragma unroll
        for (int v = 0; v < NW; ++v) {
            mp = fminf(mp, sm[(v * 2 + 0) * 32 + tid]);
            mg = fminf(mg, sm[(v * 2 + 1) * 32 + tid]);
        }
        float v = fabsf(sqrtf(fmaxf(2.f * mp, 0.f)) - sqrtf(fmaxf(2.f * mg, 0.f)));
        v += __shfl_down(v, 16, 64);
        v += __shfl_down(v, 8, 64);
        v += __shfl_down(v, 4, 64);
        v += __shfl_down(v, 2, 64);
        v += __shfl_down(v, 1, 64);
        if (tid == 0) {
            // deterministic fixed-point merge (integer adds commute exactly)
            const unsigned long long q =
                (unsigned long long)((double)v * SCALE);
            const unsigned long long old = atomicAdd(&sum[b], q);
            // data-dependent (always +1) -> orders cnt-add after sum-add
            const unsigned c = atomicAdd(cnt, 1u + (unsigned)(old >> 62));
            if (c == NBLK - 1) {
                #pragma unroll
                for (int bb = 0; bb < B; ++bb) {
                    const unsigned long long sv = atomicAdd(&sum[bb], 0ull);
                    out[bb] = (float)((double)sv * (1.0 / (SCALE * (double)S)));
                }
            }
        }
    }
}

extern "C" void kernel_launch(void* const* d_in, const int* in_sizes, int n_in,
                              void* d_out, int out_size, void* d_ws, size_t ws_size,
                              hipStream_t stream) {
    const float* grid  = (const float*)d_in[0];
    const float* gts   = (const float*)d_in[1];
    const float* preds = (const float*)d_in[2];
    float* out = (float*)d_out;

    unsigned long long* sum = (unsigned long long*)d_ws;   // 4 x u64
    unsigned* cnt = (unsigned*)((char*)d_ws + 32);         // 1 x u32

    hipMemsetAsync(d_ws, 0, 64, stream);   // zero sums + counter each call

    dim3 g1(S / 32, B);                    // (128, 4) = 512 blocks, 2/CU
    sdf_mfma<<<g1, BLK, 0, stream>>>(grid, gts, preds, sum, cnt, out);
}

// Round 15
// 14.130 us; speedup vs baseline: 2.1375x; 2.1375x over previous
//
#include <hip/hip_runtime.h>
#include <math.h>

#define B 4
#define S 4096
#define N 4096
#define BLK 512            // 8 waves; 2 independent blocks/CU
#define NW 8
#define W 2                // two 32-col B-frags -> 64 s per block
#define PASS 2048          // half of N: this block's j-range (32 KB x 2 clouds LDS)
#define JTW 8              // j-tiles (32 rows) per wave = PASS/32/NW
#define INF 3.4e38f

typedef _Float16 f16x8  __attribute__((ext_vector_type(8)));
typedef float    f32x16 __attribute__((ext_vector_type(16)));

// 32x32x16 K-packed Gram MFMA (mapping verified R12/R13). Each block: 64 s
// x one half of N. partial[h][cloud][b][s] = hx + min_j (hy - x.y) (fp32,
// fully overwritten each call -> poison-safe, no memset/atomics).
// A (cloud pt j): {-y0,-y1,-y2, hy_hi, hy_lo, 0,0,0}
// B (grid s, cols=lane&31): lanes<32 {x0,x1,x2,1,1,0,0,0}; lanes>=32 zero
// (kills A's k=8..15 garbage).
__global__ __launch_bounds__(BLK, 4) void sdf_mfma(
    const float* __restrict__ grid,   // [B,S,3]
    const float* __restrict__ gts,    // [B,N,3]
    const float* __restrict__ preds,  // [B,N,3]
    float* __restrict__ partial)      // [2][2][B][S]
{
    __shared__ float4 Ap[PASS];       // 32 KB
    __shared__ float4 Ag[PASS];       // 32 KB

    const int tid   = threadIdx.x;
    const int lane  = tid & 63;
    const int wv    = tid >> 6;       // 0..7
    const int l31   = lane & 31;
    const int stile = blockIdx.x;     // 64 tiles of 64 s
    const int h     = blockIdx.y;     // half of N
    const int b     = blockIdx.z;
    const int scol  = stile * 64;

    // ---- B-frags + hx ----
    const bool lo32 = (lane < 32);
    f16x8 bf[W];
    float hx[W];
    #pragma unroll
    for (int w = 0; w < W; ++w) {
        const float* xp = grid + ((size_t)b * S + scol + w * 32 + l31) * 3;
        float x0 = (float)(_Float16)xp[0];
        float x1 = (float)(_Float16)xp[1];
        float x2 = (float)(_Float16)xp[2];
        hx[w] = 0.5f * (x0 * x0 + x1 * x1 + x2 * x2);
        f16x8 bb = { (_Float16)x0, (_Float16)x1, (_Float16)x2,
                     (_Float16)1.f, (_Float16)1.f,
                     (_Float16)0.f, (_Float16)0.f, (_Float16)0.f };
        f16x8 z  = { (_Float16)0.f, (_Float16)0.f, (_Float16)0.f, (_Float16)0.f,
                     (_Float16)0.f, (_Float16)0.f, (_Float16)0.f, (_Float16)0.f };
        bf[w] = lo32 ? bb : z;
    }

    // ---- stage + pack this half (4 pts per cloud per thread) ----
    {
        const float4* srcP = (const float4*)(preds + (size_t)b * N * 3);
        const float4* srcG = (const float4*)(gts   + (size_t)b * N * 3);
        const int fo = h * (PASS * 3 / 4) + 3 * tid;
        float4 r0 = srcP[fo], r1 = srcP[fo + 1], r2 = srcP[fo + 2];
        const float ys[4][3] = { { r0.x, r0.y, r0.z }, { r0.w, r1.x, r1.y },
                                 { r1.z, r1.w, r2.x }, { r2.y, r2.z, r2.w } };
        #pragma unroll
        for (int k = 0; k < 4; ++k) {
            float y0 = (float)(_Float16)ys[k][0];
            float y1 = (float)(_Float16)ys[k][1];
            float y2 = (float)(_Float16)ys[k][2];
            float hy = 0.5f * (y0 * y0 + y1 * y1 + y2 * y2);
            _Float16 hh = (_Float16)hy;
            _Float16 hl = (_Float16)(hy - (float)hh);
            f16x8 a = { (_Float16)(-y0), (_Float16)(-y1), (_Float16)(-y2),
                        hh, hl, (_Float16)0.f, (_Float16)0.f, (_Float16)0.f };
            *(f16x8*)&Ap[4 * tid + k] = a;
        }
        r0 = srcG[fo]; r1 = srcG[fo + 1]; r2 = srcG[fo + 2];
        const float yg[4][3] = { { r0.x, r0.y, r0.z }, { r0.w, r1.x, r1.y },
                                 { r1.z, r1.w, r2.x }, { r2.y, r2.z, r2.w } };
        #pragma unroll
        for (int k = 0; k < 4; ++k) {
            float y0 = (float)(_Float16)yg[k][0];
            float y1 = (float)(_Float16)yg[k][1];
            float y2 = (float)(_Float16)yg[k][2];
            float hy = 0.5f * (y0 * y0 + y1 * y1 + y2 * y2);
            _Float16 hh = (_Float16)hy;
            _Float16 hl = (_Float16)(hy - (float)hh);
            f16x8 g = { (_Float16)(-y0), (_Float16)(-y1), (_Float16)(-y2),
                        hh, hl, (_Float16)0.f, (_Float16)0.f, (_Float16)0.f };
            *(f16x8*)&Ag[4 * tid + k] = g;
        }
    }
    __syncthreads();

    const f32x16 zc = { 0.f, 0.f, 0.f, 0.f, 0.f, 0.f, 0.f, 0.f,
                        0.f, 0.f, 0.f, 0.f, 0.f, 0.f, 0.f, 0.f };
    float accp[W], accg[W];
    #pragma unroll
    for (int w = 0; w < W; ++w) { accp[w] = INF; accg[w] = INF; }

    // ---- compute: wave's JTW j-tiles of 32 rows ----
    const char* app = (const char*)Ap + ((size_t)wv * JTW * 32 + l31) * 16;
    const char* agp = (const char*)Ag + ((size_t)wv * JTW * 32 + l31) * 16;
    #pragma unroll 4
    for (int jt = 0; jt < JTW; ++jt) {
        const f16x8 afp = *(const f16x8*)(app + jt * 512);
        const f16x8 afg = *(const f16x8*)(agp + jt * 512);
        #pragma unroll
        for (int w = 0; w < W; ++w) {
            f32x16 d = __builtin_amdgcn_mfma_f32_32x32x16_f16(afp, bf[w], zc, 0, 0, 0);
            float a = accp[w];
            a = fminf(fminf(a, d[0]),  d[1]);    // v_min3 shapes
            a = fminf(fminf(a, d[2]),  d[3]);
            a = fminf(fminf(a, d[4]),  d[5]);
            a = fminf(fminf(a, d[6]),  d[7]);
            a = fminf(fminf(a, d[8]),  d[9]);
            a = fminf(fminf(a, d[10]), d[11]);
            a = fminf(fminf(a, d[12]), d[13]);
            a = fminf(fminf(a, d[14]), d[15]);
            accp[w] = a;
        }
        #pragma unroll
        for (int w = 0; w < W; ++w) {
            f32x16 d = __builtin_amdgcn_mfma_f32_32x32x16_f16(afg, bf[w], zc, 0, 0, 0);
            float a = accg[w];
            a = fminf(fminf(a, d[0]),  d[1]);
            a = fminf(fminf(a, d[2]),  d[3]);
            a = fminf(fminf(a, d[4]),  d[5]);
            a = fminf(fminf(a, d[6]),  d[7]);
            a = fminf(fminf(a, d[8]),  d[9]);
            a = fminf(fminf(a, d[10]), d[11]);
            a = fminf(fminf(a, d[12]), d[13]);
            a = fminf(fminf(a, d[14]), d[15]);
            accg[w] = a;
        }
    }
    __syncthreads();   // all reads done; Ap reusable as sm

    // ---- cross-lane (row halves) + cross-wave fold, store partials ----
    float* sm = (float*)Ap;   // [NW][2][64]
    #pragma unroll
    for (int w = 0; w < W; ++w) {
        float mp = fminf(accp[w], __shfl_xor(accp[w], 32, 64));
        float mg = fminf(accg[w], __shfl_xor(accg[w], 32, 64));
        if (lo32) {
            sm[(wv * 2 + 0) * 64 + w * 32 + l31] = hx[w] + mp;
            sm[(wv * 2 + 1) * 64 + w * 32 + l31] = hx[w] + mg;
        }
    }
    __syncthreads();
    if (tid < 64) {
        float mp = INF, mg = INF;
        #pragma unroll
        for (int v = 0; v < NW; ++v) {
            mp = fminf(mp, sm[(v * 2 + 0) * 64 + tid]);
            mg = fminf(mg, sm[(v * 2 + 1) * 64 + tid]);
        }
        const size_t s = (size_t)scol + tid;
        partial[(((size_t)h * 2 + 0) * B + b) * S + s] = mp;
        partial[(((size_t)h * 2 + 1) * B + b) * S + s] = mg;
    }
}

// Kernel 2: one block per batch; min over halves, d=sqrt(max(2u,0)), |diff|,
// block-sum over S -> out[b]. float4 reads (S/4 = 1024 per slice).
__global__ __launch_bounds__(1024) void sdf_final(
    const float* __restrict__ partial, float* __restrict__ out)
{
    const int b   = blockIdx.x;
    const int tid = threadIdx.x;      // 0..1023 ; one float4 (4 s) per thread

    const float4* p00 = (const float4*)(partial + ((size_t)0 * B + b) * S);
    const float4* p01 = (const float4*)(partial + ((size_t)1 * B + b) * S);
    const float4* p10 = (const float4*)(partial + ((size_t)2 * B + b) * S);
    const float4* p11 = (const float4*)(partial + ((size_t)3 * B + b) * S);

    const float4 a0 = p00[tid], a1 = p10[tid];   // cloud 0 (preds), halves
    const float4 b0 = p01[tid], b1 = p11[tid];   // cloud 1 (gts), halves

    float v = 0.f;
    {
        float mp = fminf(a0.x, a1.x), mg = fminf(b0.x, b1.x);
        v += fabsf(sqrtf(fmaxf(2.f * mp, 0.f)) - sqrtf(fmaxf(2.f * mg, 0.f)));
        mp = fminf(a0.y, a1.y); mg = fminf(b0.y, b1.y);
        v += fabsf(sqrtf(fmaxf(2.f * mp, 0.f)) - sqrtf(fmaxf(2.f * mg, 0.f)));
        mp = fminf(a0.z, a1.z); mg = fminf(b0.z, b1.z);
        v += fabsf(sqrtf(fmaxf(2.f * mp, 0.f)) - sqrtf(fmaxf(2.f * mg, 0.f)));
        mp = fminf(a0.w, a1.w); mg = fminf(b0.w, b1.w);
        v += fabsf(sqrtf(fmaxf(2.f * mp, 0.f)) - sqrtf(fmaxf(2.f * mg, 0.f)));
    }

    #pragma unroll
    for (int off = 32; off > 0; off >>= 1)
        v += __shfl_down(v, off, 64);

    __shared__ float wsum[16];
    if ((tid & 63) == 0) wsum[tid >> 6] = v;
    __syncthreads();
    if (tid == 0) {
        float t = 0.f;
        #pragma unroll
        for (int w = 0; w < 16; ++w) t += wsum[w];
        out[b] = t / (float)S;
    }
}

extern "C" void kernel_launch(void* const* d_in, const int* in_sizes, int n_in,
                              void* d_out, int out_size, void* d_ws, size_t ws_size,
                              hipStream_t stream) {
    const float* grid  = (const float*)d_in[0];
    const float* gts   = (const float*)d_in[1];
    const float* preds = (const float*)d_in[2];
    float* out = (float*)d_out;
    float* partial = (float*)d_ws;    // [2][2][B][S] fp32 = 256 KB

    dim3 g1(S / 64, 2, B);            // (64, 2, 4) = 512 blocks, 2/CU
    sdf_mfma<<<g1, BLK, 0, stream>>>(grid, gts, preds, partial);

    sdf_final<<<B, 1024, 0, stream>>>(partial, out);
}